// Round 3
// baseline (246.785 us; speedup 1.0000x reference)
//
#include <hip/hip_runtime.h>

// GCN encoder: out = prelu( (Dinv A_hat Dinv X) W^T + b ).
// R10: fused gather+GEMM with occupancy fix. M-tile 64 (grid 782 = machine
// stays full), B-fragments read directly from L2-resident Wb (no Bs LDS),
// LDS = As only (17.4 KB) -> 3 blocks/CU, 12 waves/CU in the latency-bound
// gather phase (2x R9). R9 post-mortem: 391-block fused grid ran at ~6
// waves/CU, cancelling the ag-traffic win (ag was L3-resident anyway).

#define F_IN 128
#define H_OUT 512

typedef __bf16 bf16x8 __attribute__((ext_vector_type(8)));
typedef float  f32x4  __attribute__((ext_vector_type(4)));

// Multi-role prep: blocks [0,NWB) cast W->bf16; [NWB,NWB+NXB) cast x->bf16;
// rest count in-degrees, recording each edge's intra-segment position.
__global__ __launch_bounds__(256) void prep_kernel(const float* __restrict__ W,
                                                   __bf16* __restrict__ Wb, int nw8,
                                                   const float* __restrict__ x,
                                                   __bf16* __restrict__ xs, int nx8,
                                                   const int* __restrict__ col,
                                                   unsigned* __restrict__ deg,
                                                   unsigned* __restrict__ pos, int E,
                                                   int NWB, int NXB) {
    const int b = blockIdx.x, t = threadIdx.x;
    if (b < NWB) {
        int i = b * 256 + t;
        if (i >= nw8) return;
        float4 a0 = ((const float4*)W)[i * 2];
        float4 a1 = ((const float4*)W)[i * 2 + 1];
        bf16x8 v;
        v[0] = (__bf16)a0.x; v[1] = (__bf16)a0.y; v[2] = (__bf16)a0.z; v[3] = (__bf16)a0.w;
        v[4] = (__bf16)a1.x; v[5] = (__bf16)a1.y; v[6] = (__bf16)a1.z; v[7] = (__bf16)a1.w;
        ((bf16x8*)Wb)[i] = v;
    } else if (b < NWB + NXB) {
        int i = (b - NWB) * 256 + t;
        if (i >= nx8) return;
        float4 a0 = ((const float4*)x)[i * 2];
        float4 a1 = ((const float4*)x)[i * 2 + 1];
        bf16x8 v;
        v[0] = (__bf16)a0.x; v[1] = (__bf16)a0.y; v[2] = (__bf16)a0.z; v[3] = (__bf16)a0.w;
        v[4] = (__bf16)a1.x; v[5] = (__bf16)a1.y; v[6] = (__bf16)a1.z; v[7] = (__bf16)a1.w;
        ((bf16x8*)xs)[i] = v;
    } else {
        int e = (b - NWB - NXB) * 256 + t;
        if (e < E) pos[e] = atomicAdd(&deg[col[e]], 1u);  // returns old = position
    }
}

// Order-free CSR segment assignment: wave-scan of 8-ALIGNED deg, one atomic
// per wave. Aligned segment starts -> adj+rowptr[i] is 32B-aligned, enabling
// int4 adj loads in the gather. Gaps hold garbage; gather predicates them off.
__global__ __launch_bounds__(256) void assign_kernel(const unsigned* __restrict__ deg,
                                                     unsigned* __restrict__ total,
                                                     int* __restrict__ rowptr,
                                                     float* __restrict__ dinv, int n) {
    const int i = blockIdx.x * 256 + threadIdx.x;
    const int lane = threadIdx.x & 63;
    unsigned d = (i < n) ? deg[i] : 0u;
    unsigned da = (d + 7u) & ~7u;           // 8-aligned segment size
    unsigned x = da;
    #pragma unroll
    for (int o = 1; o < 64; o <<= 1) {
        unsigned y = __shfl_up(x, (unsigned)o, 64);
        if (lane >= o) x += y;
    }
    unsigned tot = __shfl(x, 63, 64);       // wave total (aligned)
    unsigned wb = 0;
    if (lane == 63) wb = atomicAdd(total, tot);
    wb = __shfl(wb, 63, 64);                // wave base
    if (i < n) {
        rowptr[i] = (int)(wb + x - da);     // aligned segment start
        dinv[i]   = rsqrtf((float)(d + 1u));  // +1 self-loop
    }
}

// Atomic-free fill: adj[rowptr[col[e]] + pos[e]] = row[e].
__global__ __launch_bounds__(256) void fill_csr_kernel(const int* __restrict__ row,
                                                       const int* __restrict__ col,
                                                       const unsigned* __restrict__ pos,
                                                       const int* __restrict__ rowptr,
                                                       int* __restrict__ adj, int E) {
    int e = blockIdx.x * 256 + threadIdx.x;
    if (e >= E) return;
    adj[rowptr[col[e]] + (int)pos[e]] = row[e];
}

// Fused gather-aggregate + GEMM + bias + PReLU, 64-row M-tile.
// Phase 1: 16 node-slots x 16 lanes gather 64 node rows into As (bf16).
//   Fully predicated 8-wide edge loop (dead slots -> self row, weight 0).
// Phase 2: per wave, A-frags (16 rows) hoisted to regs; B-fragments read
//   DIRECTLY from L2-resident Wb (128 KB total; no LDS staging); 4 col-tiles
//   of 128; epilogue adds bias, applies PReLU, stores fp32.
__global__ __launch_bounds__(256, 3) void fused_agg_gemm_kernel(
        const int* __restrict__ rowptr, const unsigned* __restrict__ deg,
        const int* __restrict__ adj, const __bf16* __restrict__ xs,
        const float* __restrict__ dinv, const __bf16* __restrict__ Wb,
        const float* __restrict__ bias, const float* __restrict__ alpha,
        float* __restrict__ out, int N) {
    __shared__ __bf16 As[64][136];  // 17.4 KB; +8 pad keeps frag reads ~2-way (free)

    const int rb = blockIdx.x * 64;
    const int t  = threadIdx.x;
    const int li   = t & 15;        // lane-in-node: 16B chunk index
    const int slot = t >> 4;        // node slot 0..15

    const bf16x8* xs8 = (const bf16x8*)xs;  // 16 chunks per row

    // ---- Phase 1: gather 64 nodes into As ----
    #pragma unroll
    for (int nl = slot; nl < 64; nl += 16) {
        const int node = rb + nl;
        bf16x8 o;
        if (node < N) {
            const float dvn = dinv[node];
            bf16x8 sv = xs8[(size_t)node * 16 + li];
            float acc[8];
            #pragma unroll
            for (int q = 0; q < 8; ++q) acc[q] = dvn * (float)sv[q];

            const int s = rowptr[node];
            const int e = s + (int)deg[node];
            for (int j = s; j < e; j += 8) {
                int4 ra  = *(const int4*)(adj + j);      // 32B-aligned segment
                int4 rb4 = *(const int4*)(adj + j + 4);
                int rr[8];
                rr[0] = ra.x;  rr[1] = ra.y;  rr[2] = ra.z;  rr[3] = ra.w;
                rr[4] = rb4.x; rr[5] = rb4.y; rr[6] = rb4.z; rr[7] = rb4.w;
                float wgt[8]; bf16x8 v[8];
                #pragma unroll
                for (int u = 0; u < 8; ++u) {
                    const bool ok = (j + u) < e;
                    const int r = ok ? rr[u] : node;  // dead slot -> self (cached)
                    wgt[u] = ok ? dinv[r] : 0.0f;
                    v[u]   = xs8[(size_t)r * 16 + li];
                }
                #pragma unroll
                for (int u = 0; u < 8; ++u) {
                    #pragma unroll
                    for (int q = 0; q < 8; ++q) acc[q] += wgt[u] * (float)v[u][q];
                }
            }
            #pragma unroll
            for (int q = 0; q < 8; ++q) o[q] = (__bf16)(acc[q] * dvn);
        } else {
            #pragma unroll
            for (int q = 0; q < 8; ++q) o[q] = (__bf16)0.0f;
        }
        *(bf16x8*)&As[nl][li * 8] = o;
    }
    __syncthreads();

    // ---- Phase 2: GEMM against 4 col-tiles of W (B direct from global) ----
    const int w    = t >> 6;        // wave: owns m-rows w*16..w*16+15
    const int lane = t & 63;
    const int lrow = lane & 15;
    const int lk   = (lane >> 4) * 8;
    const int rloc = (lane >> 4) * 4;

    // Hoist A fragments: read each As element from LDS exactly once.
    bf16x8 af[4];
    #pragma unroll
    for (int ks = 0; ks < 4; ++ks)
        af[ks] = *(const bf16x8*)&As[w * 16 + lrow][ks * 32 + lk];

    #pragma unroll
    for (int ct = 0; ct < 4; ++ct) {
        const int cb = ct * 128;

        f32x4 acc[8] = {};
        #pragma unroll
        for (int ks = 0; ks < 4; ++ks) {
            const int k0 = ks * 32 + lk;
            #pragma unroll
            for (int tn = 0; tn < 8; ++tn) {
                bf16x8 bfr = *(const bf16x8*)(Wb + (size_t)(cb + tn * 16 + lrow) * F_IN + k0);
                acc[tn] = __builtin_amdgcn_mfma_f32_16x16x32_bf16(af[ks], bfr, acc[tn], 0, 0, 0);
            }
        }

        // Epilogue: bias + PReLU; C/D layout col=lane&15, row=(lane>>4)*4+reg.
        float bb[8], aa[8];
        #pragma unroll
        for (int tn = 0; tn < 8; ++tn) {
            int n = cb + tn * 16 + lrow;
            bb[tn] = bias[n];
            aa[tn] = alpha[n];
        }
        #pragma unroll
        for (int r = 0; r < 4; ++r) {
            int m = rb + w * 16 + rloc + r;
            if (m >= N) continue;
            #pragma unroll
            for (int tn = 0; tn < 8; ++tn) {
                int n = cb + tn * 16 + lrow;
                float v = acc[tn][r] + bb[tn];
                v = v > 0.f ? v : aa[tn] * v;
                out[(size_t)m * H_OUT + n] = v;
            }
        }
    }
}

extern "C" void kernel_launch(void* const* d_in, const int* in_sizes, int n_in,
                              void* d_out, int out_size, void* d_ws, size_t ws_size,
                              hipStream_t stream) {
    const float* x     = (const float*)d_in[0];
    const int*   ei    = (const int*)d_in[1];
    const float* W     = (const float*)d_in[2];
    const float* b     = (const float*)d_in[3];
    const float* alpha = (const float*)d_in[4];
    float*       out   = (float*)d_out;

    const int N = in_sizes[0] / F_IN;
    const int E = in_sizes[1] / 2;
    const int* row = ei;         // source
    const int* col = ei + E;     // target

    // Workspace layout (64B-aligned sections).
    char* wsb = (char*)d_ws;
    size_t off = 0;
    __bf16* xs = (__bf16*)(wsb + off);  off += (size_t)N * F_IN * 2;     off = (off + 63) & ~(size_t)63;
    __bf16* Wb = (__bf16*)(wsb + off);  off += (size_t)H_OUT * F_IN * 2; off = (off + 63) & ~(size_t)63;
    unsigned* deg    = (unsigned*)(wsb + off);  off += (size_t)(N + 1) * 4;  // deg[N] = scan total
    float*    dinv   = (float*)(wsb + off);     off += (size_t)N * 4;
    int*      rowptr = (int*)(wsb + off);       off += (size_t)N * 4;
    off = (off + 63) & ~(size_t)63;
    unsigned* pos = (unsigned*)(wsb + off);     off += (size_t)E * 4;
    off = (off + 63) & ~(size_t)63;
    int* adj = (int*)(wsb + off);   // aligned CSR: up to E + 8N ints
    unsigned* total = deg + N;

    const int nw8 = H_OUT * F_IN / 8;
    const int nx8 = N * F_IN / 8;
    const int NWB = (nw8 + 255) / 256;
    const int NXB = (nx8 + 255) / 256;
    const int NEB = (E + 255) / 256;

    // 1. zero deg + scan total
    hipMemsetAsync(deg, 0, (size_t)(N + 1) * 4, stream);
    // 2. cast W, cast x, count deg + record positions
    prep_kernel<<<NWB + NXB + NEB, 256, 0, stream>>>(W, Wb, nw8, x, xs, nx8,
                                                     col, deg, pos, E, NWB, NXB);
    // 3. aligned segment assignment + dinv
    assign_kernel<<<(N + 255) / 256, 256, 0, stream>>>(deg, total, rowptr, dinv, N);
    // 4. atomic-free fill
    fill_csr_kernel<<<(E + 255) / 256, 256, 0, stream>>>(row, col, pos, rowptr, adj, E);
    // 5. fused gather-aggregate + GEMM + bias + PReLU (64-row tiles)
    fused_agg_gemm_kernel<<<(N + 63) / 64, 256, 0, stream>>>(
        rowptr, deg, adj, xs, dinv, Wb, b, alpha, out, N);
}

// Round 4
// 220.085 us; speedup vs baseline: 1.1213x; 1.1213x over previous
//
#include <hip/hip_runtime.h>

// GCN encoder: out = prelu( (Dinv A_hat Dinv X) W^T + b ).
// R11: fused gather+GEMM, M-tile 64, with B staged in LDS per col-tile.
// R10 post-mortem: B-fragments direct from global put ~200cy L2 loads in
// front of every MFMA (MfmaUtil 2.7%, VALU 13%, hbm 21% => latency-bound);
// each wave also re-read the 32KB W tile 4x. Now: As(17.4K)+Bs(34.8K)=52.2KB
// -> 3 blocks/CU (12 waves/CU), B staged cooperatively once per tile, MFMA
// reads via ds_read_b128 (~12cy).

#define F_IN 128
#define H_OUT 512

typedef __bf16 bf16x8 __attribute__((ext_vector_type(8)));
typedef float  f32x4  __attribute__((ext_vector_type(4)));

// Multi-role prep: blocks [0,NWB) cast W->bf16; [NWB,NWB+NXB) cast x->bf16;
// rest count in-degrees, recording each edge's intra-segment position.
__global__ __launch_bounds__(256) void prep_kernel(const float* __restrict__ W,
                                                   __bf16* __restrict__ Wb, int nw8,
                                                   const float* __restrict__ x,
                                                   __bf16* __restrict__ xs, int nx8,
                                                   const int* __restrict__ col,
                                                   unsigned* __restrict__ deg,
                                                   unsigned* __restrict__ pos, int E,
                                                   int NWB, int NXB) {
    const int b = blockIdx.x, t = threadIdx.x;
    if (b < NWB) {
        int i = b * 256 + t;
        if (i >= nw8) return;
        float4 a0 = ((const float4*)W)[i * 2];
        float4 a1 = ((const float4*)W)[i * 2 + 1];
        bf16x8 v;
        v[0] = (__bf16)a0.x; v[1] = (__bf16)a0.y; v[2] = (__bf16)a0.z; v[3] = (__bf16)a0.w;
        v[4] = (__bf16)a1.x; v[5] = (__bf16)a1.y; v[6] = (__bf16)a1.z; v[7] = (__bf16)a1.w;
        ((bf16x8*)Wb)[i] = v;
    } else if (b < NWB + NXB) {
        int i = (b - NWB) * 256 + t;
        if (i >= nx8) return;
        float4 a0 = ((const float4*)x)[i * 2];
        float4 a1 = ((const float4*)x)[i * 2 + 1];
        bf16x8 v;
        v[0] = (__bf16)a0.x; v[1] = (__bf16)a0.y; v[2] = (__bf16)a0.z; v[3] = (__bf16)a0.w;
        v[4] = (__bf16)a1.x; v[5] = (__bf16)a1.y; v[6] = (__bf16)a1.z; v[7] = (__bf16)a1.w;
        ((bf16x8*)xs)[i] = v;
    } else {
        int e = (b - NWB - NXB) * 256 + t;
        if (e < E) pos[e] = atomicAdd(&deg[col[e]], 1u);  // returns old = position
    }
}

// Order-free CSR segment assignment: wave-scan of 8-ALIGNED deg, one atomic
// per wave. Aligned segment starts -> adj+rowptr[i] is 32B-aligned, enabling
// int4 adj loads in the gather. Gaps hold garbage; gather predicates them off.
__global__ __launch_bounds__(256) void assign_kernel(const unsigned* __restrict__ deg,
                                                     unsigned* __restrict__ total,
                                                     int* __restrict__ rowptr,
                                                     float* __restrict__ dinv, int n) {
    const int i = blockIdx.x * 256 + threadIdx.x;
    const int lane = threadIdx.x & 63;
    unsigned d = (i < n) ? deg[i] : 0u;
    unsigned da = (d + 7u) & ~7u;           // 8-aligned segment size
    unsigned x = da;
    #pragma unroll
    for (int o = 1; o < 64; o <<= 1) {
        unsigned y = __shfl_up(x, (unsigned)o, 64);
        if (lane >= o) x += y;
    }
    unsigned tot = __shfl(x, 63, 64);       // wave total (aligned)
    unsigned wb = 0;
    if (lane == 63) wb = atomicAdd(total, tot);
    wb = __shfl(wb, 63, 64);                // wave base
    if (i < n) {
        rowptr[i] = (int)(wb + x - da);     // aligned segment start
        dinv[i]   = rsqrtf((float)(d + 1u));  // +1 self-loop
    }
}

// Atomic-free fill: adj[rowptr[col[e]] + pos[e]] = row[e].
__global__ __launch_bounds__(256) void fill_csr_kernel(const int* __restrict__ row,
                                                       const int* __restrict__ col,
                                                       const unsigned* __restrict__ pos,
                                                       const int* __restrict__ rowptr,
                                                       int* __restrict__ adj, int E) {
    int e = blockIdx.x * 256 + threadIdx.x;
    if (e >= E) return;
    adj[rowptr[col[e]] + (int)pos[e]] = row[e];
}

// Fused gather-aggregate + GEMM + bias + PReLU, 64-row M-tile.
// Phase 1: 16 node-slots x 16 lanes gather 64 node rows into As (bf16).
//   Fully predicated 8-wide edge loop (dead slots -> self row, weight 0).
// Phase 2: A-frags hoisted to regs; 4 col-tiles of W staged cooperatively
//   into Bs (LDS); MFMA reads from LDS; epilogue bias+PReLU, fp32 stores.
__global__ __launch_bounds__(256, 3) void fused_agg_gemm_kernel(
        const int* __restrict__ rowptr, const unsigned* __restrict__ deg,
        const int* __restrict__ adj, const __bf16* __restrict__ xs,
        const float* __restrict__ dinv, const __bf16* __restrict__ Wb,
        const float* __restrict__ bias, const float* __restrict__ alpha,
        float* __restrict__ out, int N) {
    __shared__ __bf16 As[64][136];   // 17.4 KB (+8 pad)
    __shared__ __bf16 Bs[128][136];  // 34.8 KB (+8 pad) — total 52.2 KB -> 3 blk/CU

    const int rb = blockIdx.x * 64;
    const int t  = threadIdx.x;
    const int li   = t & 15;        // lane-in-node: 16B chunk index
    const int slot = t >> 4;        // node slot 0..15

    const bf16x8* xs8 = (const bf16x8*)xs;  // 16 chunks per row

    // ---- Phase 1: gather 64 nodes into As ----
    #pragma unroll
    for (int nl = slot; nl < 64; nl += 16) {
        const int node = rb + nl;
        bf16x8 o;
        if (node < N) {
            const float dvn = dinv[node];
            bf16x8 sv = xs8[(size_t)node * 16 + li];
            float acc[8];
            #pragma unroll
            for (int q = 0; q < 8; ++q) acc[q] = dvn * (float)sv[q];

            const int s = rowptr[node];
            const int e = s + (int)deg[node];
            for (int j = s; j < e; j += 8) {
                int4 ra  = *(const int4*)(adj + j);      // 32B-aligned segment
                int4 rb4 = *(const int4*)(adj + j + 4);
                int rr[8];
                rr[0] = ra.x;  rr[1] = ra.y;  rr[2] = ra.z;  rr[3] = ra.w;
                rr[4] = rb4.x; rr[5] = rb4.y; rr[6] = rb4.z; rr[7] = rb4.w;
                float wgt[8]; bf16x8 v[8];
                #pragma unroll
                for (int u = 0; u < 8; ++u) {
                    const bool ok = (j + u) < e;
                    const int r = ok ? rr[u] : node;  // dead slot -> self (cached)
                    wgt[u] = ok ? dinv[r] : 0.0f;
                    v[u]   = xs8[(size_t)r * 16 + li];
                }
                #pragma unroll
                for (int u = 0; u < 8; ++u) {
                    #pragma unroll
                    for (int q = 0; q < 8; ++q) acc[q] += wgt[u] * (float)v[u][q];
                }
            }
            #pragma unroll
            for (int q = 0; q < 8; ++q) o[q] = (__bf16)(acc[q] * dvn);
        } else {
            #pragma unroll
            for (int q = 0; q < 8; ++q) o[q] = (__bf16)0.0f;
        }
        *(bf16x8*)&As[nl][li * 8] = o;
    }
    __syncthreads();

    // ---- Phase 2: GEMM against 4 col-tiles of W (B staged in LDS) ----
    const int w    = t >> 6;        // wave: owns m-rows w*16..w*16+15
    const int lane = t & 63;
    const int lrow = lane & 15;
    const int lk   = (lane >> 4) * 8;
    const int rloc = (lane >> 4) * 4;

    // Hoist A fragments: read each As element from LDS exactly once.
    bf16x8 af[4];
    #pragma unroll
    for (int ks = 0; ks < 4; ++ks)
        af[ks] = *(const bf16x8*)&As[w * 16 + lrow][ks * 32 + lk];

    #pragma unroll
    for (int ct = 0; ct < 4; ++ct) {
        const int cb = ct * 128;

        if (ct) __syncthreads();    // prior tile's MFMA reads of Bs done
        #pragma unroll
        for (int i = 0; i < 8; ++i) {
            int c  = i * 256 + t;
            int r  = c >> 4;
            int k8 = (c & 15) * 8;
            *(bf16x8*)&Bs[r][k8] = *(const bf16x8*)(Wb + (size_t)(cb + r) * F_IN + k8);
        }
        __syncthreads();

        f32x4 acc[8] = {};
        #pragma unroll
        for (int ks = 0; ks < 4; ++ks) {
            const int k0 = ks * 32 + lk;
            #pragma unroll
            for (int tn = 0; tn < 8; ++tn) {
                bf16x8 bfr = *(const bf16x8*)&Bs[tn * 16 + lrow][k0];
                acc[tn] = __builtin_amdgcn_mfma_f32_16x16x32_bf16(af[ks], bfr, acc[tn], 0, 0, 0);
            }
        }

        // Epilogue: bias + PReLU; C/D layout col=lane&15, row=(lane>>4)*4+reg.
        float bb[8], aa[8];
        #pragma unroll
        for (int tn = 0; tn < 8; ++tn) {
            int n = cb + tn * 16 + lrow;
            bb[tn] = bias[n];
            aa[tn] = alpha[n];
        }
        #pragma unroll
        for (int r = 0; r < 4; ++r) {
            int m = rb + w * 16 + rloc + r;
            if (m >= N) continue;
            #pragma unroll
            for (int tn = 0; tn < 8; ++tn) {
                int n = cb + tn * 16 + lrow;
                float v = acc[tn][r] + bb[tn];
                v = v > 0.f ? v : aa[tn] * v;
                out[(size_t)m * H_OUT + n] = v;
            }
        }
    }
}

extern "C" void kernel_launch(void* const* d_in, const int* in_sizes, int n_in,
                              void* d_out, int out_size, void* d_ws, size_t ws_size,
                              hipStream_t stream) {
    const float* x     = (const float*)d_in[0];
    const int*   ei    = (const int*)d_in[1];
    const float* W     = (const float*)d_in[2];
    const float* b     = (const float*)d_in[3];
    const float* alpha = (const float*)d_in[4];
    float*       out   = (float*)d_out;

    const int N = in_sizes[0] / F_IN;
    const int E = in_sizes[1] / 2;
    const int* row = ei;         // source
    const int* col = ei + E;     // target

    // Workspace layout (64B-aligned sections).
    char* wsb = (char*)d_ws;
    size_t off = 0;
    __bf16* xs = (__bf16*)(wsb + off);  off += (size_t)N * F_IN * 2;     off = (off + 63) & ~(size_t)63;
    __bf16* Wb = (__bf16*)(wsb + off);  off += (size_t)H_OUT * F_IN * 2; off = (off + 63) & ~(size_t)63;
    unsigned* deg    = (unsigned*)(wsb + off);  off += (size_t)(N + 1) * 4;  // deg[N] = scan total
    float*    dinv   = (float*)(wsb + off);     off += (size_t)N * 4;
    int*      rowptr = (int*)(wsb + off);       off += (size_t)N * 4;
    off = (off + 63) & ~(size_t)63;
    unsigned* pos = (unsigned*)(wsb + off);     off += (size_t)E * 4;
    off = (off + 63) & ~(size_t)63;
    int* adj = (int*)(wsb + off);   // aligned CSR: up to E + 8N ints
    unsigned* total = deg + N;

    const int nw8 = H_OUT * F_IN / 8;
    const int nx8 = N * F_IN / 8;
    const int NWB = (nw8 + 255) / 256;
    const int NXB = (nx8 + 255) / 256;
    const int NEB = (E + 255) / 256;

    // 1. zero deg + scan total
    hipMemsetAsync(deg, 0, (size_t)(N + 1) * 4, stream);
    // 2. cast W, cast x, count deg + record positions
    prep_kernel<<<NWB + NXB + NEB, 256, 0, stream>>>(W, Wb, nw8, x, xs, nx8,
                                                     col, deg, pos, E, NWB, NXB);
    // 3. aligned segment assignment + dinv
    assign_kernel<<<(N + 255) / 256, 256, 0, stream>>>(deg, total, rowptr, dinv, N);
    // 4. atomic-free fill
    fill_csr_kernel<<<(E + 255) / 256, 256, 0, stream>>>(row, col, pos, rowptr, adj, E);
    // 5. fused gather-aggregate + GEMM + bias + PReLU (64-row tiles, Bs LDS)
    fused_agg_gemm_kernel<<<(N + 63) / 64, 256, 0, stream>>>(
        rowptr, deg, adj, xs, dinv, Wb, b, alpha, out, N);
}

// Round 5
// 209.455 us; speedup vs baseline: 1.1782x; 1.0507x over previous
//
#include <hip/hip_runtime.h>

// GCN encoder: out = prelu( (Dinv A_hat Dinv X) W^T + b ).
// R12: revert to R8's separate gather+gemm (fusion lost: in-block phase
// serialization costs more than the L3-resident ag round-trip saves).
// GEMM upgraded: one pass over ag (col-tile loop, -38MB of L3 re-reads),
// A-fragments hoisted to regs once, nontemporal out stores (102MB stream,
// never re-read -> don't pollute L2).

#define F_IN 128
#define H_OUT 512

typedef __bf16 bf16x8 __attribute__((ext_vector_type(8)));
typedef float  f32x4  __attribute__((ext_vector_type(4)));

// Multi-role prep: blocks [0,NWB) cast W->bf16; [NWB,NWB+NXB) cast x->bf16;
// rest count in-degrees, recording each edge's intra-segment position.
__global__ __launch_bounds__(256) void prep_kernel(const float* __restrict__ W,
                                                   __bf16* __restrict__ Wb, int nw8,
                                                   const float* __restrict__ x,
                                                   __bf16* __restrict__ xs, int nx8,
                                                   const int* __restrict__ col,
                                                   unsigned* __restrict__ deg,
                                                   unsigned* __restrict__ pos, int E,
                                                   int NWB, int NXB) {
    const int b = blockIdx.x, t = threadIdx.x;
    if (b < NWB) {
        int i = b * 256 + t;
        if (i >= nw8) return;
        float4 a0 = ((const float4*)W)[i * 2];
        float4 a1 = ((const float4*)W)[i * 2 + 1];
        bf16x8 v;
        v[0] = (__bf16)a0.x; v[1] = (__bf16)a0.y; v[2] = (__bf16)a0.z; v[3] = (__bf16)a0.w;
        v[4] = (__bf16)a1.x; v[5] = (__bf16)a1.y; v[6] = (__bf16)a1.z; v[7] = (__bf16)a1.w;
        ((bf16x8*)Wb)[i] = v;
    } else if (b < NWB + NXB) {
        int i = (b - NWB) * 256 + t;
        if (i >= nx8) return;
        float4 a0 = ((const float4*)x)[i * 2];
        float4 a1 = ((const float4*)x)[i * 2 + 1];
        bf16x8 v;
        v[0] = (__bf16)a0.x; v[1] = (__bf16)a0.y; v[2] = (__bf16)a0.z; v[3] = (__bf16)a0.w;
        v[4] = (__bf16)a1.x; v[5] = (__bf16)a1.y; v[6] = (__bf16)a1.z; v[7] = (__bf16)a1.w;
        ((bf16x8*)xs)[i] = v;
    } else {
        int e = (b - NWB - NXB) * 256 + t;
        if (e < E) pos[e] = atomicAdd(&deg[col[e]], 1u);  // returns old = position
    }
}

// Order-free CSR segment assignment: wave-scan of 8-ALIGNED deg, one atomic
// per wave. Aligned segment starts -> adj+rowptr[i] is 32B-aligned, enabling
// int4 adj loads in the gather. Gaps hold garbage; gather predicates them off.
__global__ __launch_bounds__(256) void assign_kernel(const unsigned* __restrict__ deg,
                                                     unsigned* __restrict__ total,
                                                     int* __restrict__ rowptr,
                                                     float* __restrict__ dinv, int n) {
    const int i = blockIdx.x * 256 + threadIdx.x;
    const int lane = threadIdx.x & 63;
    unsigned d = (i < n) ? deg[i] : 0u;
    unsigned da = (d + 7u) & ~7u;           // 8-aligned segment size
    unsigned x = da;
    #pragma unroll
    for (int o = 1; o < 64; o <<= 1) {
        unsigned y = __shfl_up(x, (unsigned)o, 64);
        if (lane >= o) x += y;
    }
    unsigned tot = __shfl(x, 63, 64);       // wave total (aligned)
    unsigned wb = 0;
    if (lane == 63) wb = atomicAdd(total, tot);
    wb = __shfl(wb, 63, 64);                // wave base
    if (i < n) {
        rowptr[i] = (int)(wb + x - da);     // aligned segment start
        dinv[i]   = rsqrtf((float)(d + 1u));  // +1 self-loop
    }
}

// Atomic-free fill: adj[rowptr[col[e]] + pos[e]] = row[e].
__global__ __launch_bounds__(256) void fill_csr_kernel(const int* __restrict__ row,
                                                       const int* __restrict__ col,
                                                       const unsigned* __restrict__ pos,
                                                       const int* __restrict__ rowptr,
                                                       int* __restrict__ adj, int E) {
    int e = blockIdx.x * 256 + threadIdx.x;
    if (e >= E) return;
    adj[rowptr[col[e]] + (int)pos[e]] = row[e];
}

// Aggregate: ag[c,:] = bf16( dinv[c] * ( dinv[c]*xs[c,:] + sum_r dinv[r]*xs[r,:] ) ).
// 16 lanes per node (16B/lane = 256B row), 4 nodes per wave.
// Single fully-predicated 8-wide loop: dead slots read the self row (L1-hot)
// with weight 0, so EVERY edge group keeps 8 gathers in flight.
__global__ __launch_bounds__(256) void gather_agg_kernel(const int* __restrict__ rowptr,
                                                         const unsigned* __restrict__ deg,
                                                         const int* __restrict__ adj,
                                                         const __bf16* __restrict__ xs,
                                                         const float* __restrict__ dinv,
                                                         __bf16* __restrict__ ag, int N) {
    const int t = threadIdx.x;
    const int node = blockIdx.x * 16 + (t >> 4);
    if (node >= N) return;
    const int li = t & 15;

    const bf16x8* xs8 = (const bf16x8*)xs;  // 16 chunks per row
    const float dvn = dinv[node];
    bf16x8 sv = xs8[(size_t)node * 16 + li];
    float acc[8];
    #pragma unroll
    for (int q = 0; q < 8; ++q) acc[q] = dvn * (float)sv[q];

    const int s = rowptr[node];
    const int e = s + (int)deg[node];
    for (int j = s; j < e; j += 8) {
        int4 ra  = *(const int4*)(adj + j);      // 32B-aligned segment
        int4 rb4 = *(const int4*)(adj + j + 4);
        int rr[8];
        rr[0] = ra.x;  rr[1] = ra.y;  rr[2] = ra.z;  rr[3] = ra.w;
        rr[4] = rb4.x; rr[5] = rb4.y; rr[6] = rb4.z; rr[7] = rb4.w;
        float wgt[8]; bf16x8 v[8];
        #pragma unroll
        for (int u = 0; u < 8; ++u) {
            const bool ok = (j + u) < e;
            const int r = ok ? rr[u] : node;   // dead slot -> self (cached)
            wgt[u] = ok ? dinv[r] : 0.0f;
            v[u]   = xs8[(size_t)r * 16 + li];
        }
        #pragma unroll
        for (int u = 0; u < 8; ++u) {
            #pragma unroll
            for (int q = 0; q < 8; ++q) acc[q] += wgt[u] * (float)v[u][q];
        }
    }

    bf16x8 o;
    #pragma unroll
    for (int q = 0; q < 8; ++q) o[q] = (__bf16)(acc[q] * dvn);
    ((bf16x8*)ag)[(size_t)node * 16 + li] = o;
}

// bf16 MFMA GEMM, one pass: out[m,:] = prelu( ag[m,:] @ W^T + b ).
// 128-row block, loops all 4 col-tiles of W through one Bs buffer.
// ag read ONCE (12.8 MB, was 51.2), A-frags hoisted, nontemporal fp32 stores.
__global__ __launch_bounds__(256) void gemm_mfma_kernel(const __bf16* __restrict__ ag,
                                                        const __bf16* __restrict__ Wb,
                                                        const float* __restrict__ bias,
                                                        const float* __restrict__ alpha,
                                                        float* __restrict__ out, int N) {
    __shared__ __bf16 As[128][136];  // +8 pad
    __shared__ __bf16 Bs[128][136];

    const int rb = blockIdx.x * 128;
    const int t  = threadIdx.x;

    // Stage As (whole K=128) and Bs for col-tile 0.
    #pragma unroll
    for (int i = 0; i < 8; ++i) {
        int c  = i * 256 + t;
        int r  = c >> 4;
        int k8 = (c & 15) * 8;
        bf16x8 v;
        #pragma unroll
        for (int j = 0; j < 8; ++j) v[j] = (__bf16)0.0f;
        if (rb + r < N) v = *(const bf16x8*)(ag + (size_t)(rb + r) * F_IN + k8);
        *(bf16x8*)&As[r][k8] = v;
    }
    #pragma unroll
    for (int i = 0; i < 8; ++i) {
        int c  = i * 256 + t;
        int r  = c >> 4;
        int k8 = (c & 15) * 8;
        *(bf16x8*)&Bs[r][k8] = *(const bf16x8*)(Wb + (size_t)r * F_IN + k8);
    }
    __syncthreads();

    const int w    = t >> 6;
    const int lane = t & 63;
    const int lrow = lane & 15;
    const int lk   = (lane >> 4) * 8;
    const int rloc = (lane >> 4) * 4;

    // Hoist A fragments: each As element read from LDS exactly once.
    bf16x8 af0[4], af1[4];
    #pragma unroll
    for (int ks = 0; ks < 4; ++ks) {
        const int k0 = ks * 32 + lk;
        af0[ks] = *(const bf16x8*)&As[w * 32 + lrow][k0];
        af1[ks] = *(const bf16x8*)&As[w * 32 + 16 + lrow][k0];
    }

    #pragma unroll
    for (int ct = 0; ct < 4; ++ct) {
        const int cb = ct * 128;

        f32x4 acc[2][8] = {};
        #pragma unroll
        for (int ks = 0; ks < 4; ++ks) {
            const int k0 = ks * 32 + lk;
            #pragma unroll
            for (int tn = 0; tn < 8; ++tn) {
                bf16x8 bfr = *(const bf16x8*)&Bs[tn * 16 + lrow][k0];
                acc[0][tn] = __builtin_amdgcn_mfma_f32_16x16x32_bf16(af0[ks], bfr, acc[0][tn], 0, 0, 0);
                acc[1][tn] = __builtin_amdgcn_mfma_f32_16x16x32_bf16(af1[ks], bfr, acc[1][tn], 0, 0, 0);
            }
        }

        // Epilogue: bias + PReLU; C/D layout col=lane&15, row=(lane>>4)*4+reg.
        // Nontemporal: out is write-once, never re-read -> bypass L2 allocation.
        float bb[8], aa[8];
        #pragma unroll
        for (int tn = 0; tn < 8; ++tn) {
            int n = cb + tn * 16 + lrow;
            bb[tn] = bias[n];
            aa[tn] = alpha[n];
        }
        #pragma unroll
        for (int tm = 0; tm < 2; ++tm) {
            #pragma unroll
            for (int r = 0; r < 4; ++r) {
                int m = rb + w * 32 + tm * 16 + rloc + r;
                if (m >= N) continue;
                #pragma unroll
                for (int tn = 0; tn < 8; ++tn) {
                    int n = cb + tn * 16 + lrow;
                    float v = acc[tm][tn][r] + bb[tn];
                    v = v > 0.f ? v : aa[tn] * v;
                    __builtin_nontemporal_store(v, &out[(size_t)m * H_OUT + n]);
                }
            }
        }

        // Swap in next col-tile of W (Bs reads above are done after this sync).
        if (ct < 3) {
            __syncthreads();
            #pragma unroll
            for (int i = 0; i < 8; ++i) {
                int c  = i * 256 + t;
                int r  = c >> 4;
                int k8 = (c & 15) * 8;
                *(bf16x8*)&Bs[r][k8] =
                    *(const bf16x8*)(Wb + (size_t)(cb + 128 + r) * F_IN + k8);
            }
            __syncthreads();
        }
    }
}

extern "C" void kernel_launch(void* const* d_in, const int* in_sizes, int n_in,
                              void* d_out, int out_size, void* d_ws, size_t ws_size,
                              hipStream_t stream) {
    const float* x     = (const float*)d_in[0];
    const int*   ei    = (const int*)d_in[1];
    const float* W     = (const float*)d_in[2];
    const float* b     = (const float*)d_in[3];
    const float* alpha = (const float*)d_in[4];
    float*       out   = (float*)d_out;

    const int N = in_sizes[0] / F_IN;
    const int E = in_sizes[1] / 2;
    const int* row = ei;         // source
    const int* col = ei + E;     // target

    // Workspace layout (64B-aligned sections).
    char* wsb = (char*)d_ws;
    size_t off = 0;
    __bf16* xs = (__bf16*)(wsb + off);  off += (size_t)N * F_IN * 2;     off = (off + 63) & ~(size_t)63;
    __bf16* ag = (__bf16*)(wsb + off);  off += (size_t)N * F_IN * 2;     off = (off + 63) & ~(size_t)63;
    __bf16* Wb = (__bf16*)(wsb + off);  off += (size_t)H_OUT * F_IN * 2; off = (off + 63) & ~(size_t)63;
    unsigned* deg    = (unsigned*)(wsb + off);  off += (size_t)(N + 1) * 4;  // deg[N] = scan total
    float*    dinv   = (float*)(wsb + off);     off += (size_t)N * 4;
    int*      rowptr = (int*)(wsb + off);       off += (size_t)N * 4;
    off = (off + 63) & ~(size_t)63;
    unsigned* pos = (unsigned*)(wsb + off);     off += (size_t)E * 4;
    off = (off + 63) & ~(size_t)63;
    int* adj = (int*)(wsb + off);   // aligned CSR: up to E + 8N ints
    unsigned* total = deg + N;

    const int nw8 = H_OUT * F_IN / 8;
    const int nx8 = N * F_IN / 8;
    const int NWB = (nw8 + 255) / 256;
    const int NXB = (nx8 + 255) / 256;
    const int NEB = (E + 255) / 256;

    // 1. zero deg + scan total
    hipMemsetAsync(deg, 0, (size_t)(N + 1) * 4, stream);
    // 2. cast W, cast x, count deg + record positions
    prep_kernel<<<NWB + NXB + NEB, 256, 0, stream>>>(W, Wb, nw8, x, xs, nx8,
                                                     col, deg, pos, E, NWB, NXB);
    // 3. aligned segment assignment + dinv
    assign_kernel<<<(N + 255) / 256, 256, 0, stream>>>(deg, total, rowptr, dinv, N);
    // 4. atomic-free fill
    fill_csr_kernel<<<(E + 255) / 256, 256, 0, stream>>>(row, col, pos, rowptr, adj, E);
    // 5. weighted gather-aggregate (predicated 8-wide, full occupancy)
    gather_agg_kernel<<<(N + 15) / 16, 256, 0, stream>>>(rowptr, deg, adj, xs, dinv, ag, N);
    // 6. one-pass MFMA GEMM + bias + PReLU (nontemporal stores)
    gemm_mfma_kernel<<<(N + 127) / 128, 256, 0, stream>>>(ag, Wb, b, alpha, out, N);
}